// Round 18
// baseline (316.448 us; speedup 1.0000x reference)
//
#include <hip/hip_runtime.h>
#include <hip/hip_bf16.h>
#include <stdint.h>

#define Bb 32
#define Tt 2048
#define Dd 1024   // D_IN = D_H = D_OUT

typedef float    f32x4 __attribute__((ext_vector_type(4)));
typedef _Float16 f16x8 __attribute__((ext_vector_type(8)));
typedef uint32_t u32;

// ---- ws layout (bytes) ----
// 0        w2_ws  [32][1024] f32  (2 * s.W_a)          128K
// 131072   a_ws   [32][2048] f32                       256K
// 393216   UNION: e_part [4 obb][32 b][2048 t] f32 (1M, k_e->k_sm)
//                 cpart  [32 tc][32 b][1024] f32 (4M, k_c1->k_c2)
// 4587520  U_ts   tiled fp16 U^T (see k_ut)            2M
#define WS_A     131072
#define WS_EP    393216
#define WS_UT    4587520

__device__ __forceinline__ void gll16(const void* g, const void* lds) {
  __builtin_amdgcn_global_load_lds(
      (const __attribute__((address_space(1))) u32*)(uintptr_t)g,
      (__attribute__((address_space(3))) u32*)(uint32_t)(uintptr_t)lds,
      16, 0, 0);
}

// ---------------- kernel 1: w2[b][o] = 2 * sum_i s[b][i] * W[i][o] ----------------
__global__ __launch_bounds__(256) void k_ws(const float* __restrict__ s,
                                            const float* __restrict__ W,
                                            float* __restrict__ w2_ws) {
  const int b = blockIdx.x >> 2;
  const int o = (blockIdx.x & 3) * 256 + threadIdx.x;
  __shared__ float s_sh[Dd];
#pragma unroll
  for (int j = 0; j < 4; ++j)
    s_sh[threadIdx.x + 256 * j] = s[b * Dd + threadIdx.x + 256 * j];
  __syncthreads();
  float acc = 0.f;
#pragma unroll 8
  for (int i = 0; i < Dd; ++i) acc += s_sh[i] * W[(size_t)i * Dd + o];
  w2_ws[b * Dd + o] = 2.f * acc;
}

// ------- kernel 2: build U_ts, tile-major linear-lane layout (unchanged) -------
// Tile (ob 0..7, ks 0..15) = 16KB at (ob*16+ks)*16384; element (o_l, k_l):
// byte = (k_l>>5)*8192 + (o_l>>6)*4096 + ((o_l>>4)&3)*1024
//        + (((k_l>>3)&3)*16 + (o_l&15))*16 + (k_l&7)*2
__global__ __launch_bounds__(256) void k_ut(const float* __restrict__ U,
                                            uint8_t* __restrict__ U_ts) {
  const int i0 = (blockIdx.x >> 4) * 64;   // k-tile
  const int o0 = (blockIdx.x & 15) * 64;   // o-tile
  __shared__ float tile[64][65];           // [o_loc][k_loc]
  const int tx = threadIdx.x & 63;
  const int ty = threadIdx.x >> 6;
#pragma unroll
  for (int jj = 0; jj < 16; ++jj)
    tile[tx][ty + 4 * jj] = U[(size_t)(i0 + ty + 4 * jj) * Dd + o0 + tx];
  __syncthreads();
#pragma unroll
  for (int it = 0; it < 2; ++it) {
    const int g  = it * 256 + threadIdx.x;  // 0..511
    const int ol = g & 63;
    const int kg = g >> 6;                  // 0..7
    const int o  = o0 + ol;
    const int k  = i0 + kg * 8;
    f16x8 r;
#pragma unroll
    for (int m = 0; m < 8; ++m) r[m] = (_Float16)tile[ol][kg * 8 + m];
    const int ob  = o >> 7, ks = k >> 6;
    const int o_l = o & 127, k_l = k & 63;
    const size_t byte = ((size_t)(ob * 16 + ks) << 14)
                      + (size_t)((k_l >> 5) * 8192 + (o_l >> 6) * 4096
                      + ((o_l >> 4) & 3) * 1024
                      + (((k_l >> 3) & 3) * 16 + (o_l & 15)) * 16);
    *(f16x8*)(U_ts + byte) = r;
  }
}

// ---------------- kernel 3: fused GEMM, counted-vmcnt interleaved schedule ----------------
// R16 geometry (512 thr, 8 waves tw/ow, 128t x 256o, acc[4][4], verified swizzles),
// A & B LDS double-buffered, ONE barrier/step. vmcnt INVARIANT (per wave, derived):
//   step top: outstanding = A(ks) 4 gll16 [oldest] + B(ks+1) 4 dwordx4 [newest]
//   -> s_waitcnt vmcnt(4) retires A(ks), keeps B(ks+1) in flight (never drains).
// (R17's vmcnt(8) was a no-op at 8 outstanding -> A-DMA race -> NaN. Fixed.)
// Prologue issues B(0) loads BEFORE A(0) gll16 so the cvt's reg-dep wait
// (vmcnt(4)) leaves A(0) in flight and the ks=0 invariant holds.
__global__ __launch_bounds__(512, 2) void k_e(const float* __restrict__ h,
                                              const uint8_t* __restrict__ U_ts,
                                              const float* __restrict__ w2_ws,
                                              const float* __restrict__ v_a,
                                              float* __restrict__ e_part) {
  const int blk = blockIdx.x;
  const int b   = blk >> 6;
  const int obb = (blk >> 4) & 3;   // 256-o block
  const int tb  = blk & 15;         // 128-t tile (fastest -> obb-sharers same XCD)
  const int tid  = threadIdx.x;
  const int lane = tid & 63;
  const int w    = tid >> 6;   // 0..7
  const int tw   = w >> 2;     // t-half
  const int ow   = w & 3;      // o-quarter

  __shared__ __align__(16) uint8_t Al[2][32768];
  __shared__ __align__(16) uint8_t Bl[2][16384];
  __shared__ float exch[512];

  // ---- A staging addressing: 4 gll16/thread; q -> tile (obb*2 + (q>>1)) ----
  const uint8_t* Asrc[4];
#pragma unroll
  for (int q = 0; q < 4; ++q)
    Asrc[q] = U_ts + ((size_t)((obb * 2 + (q >> 1)) * 16) << 14)
            + (size_t)(((q & 1) * 512 + w * 64 + lane) * 16);

  // ---- B addressing: 2 units/thread: u = j*512+tid -> t_l = u>>3, kg = u&7 ----
  const float* hb[2];
  int baddr[2];
#pragma unroll
  for (int j = 0; j < 2; ++j) {
    const int u   = j * 512 + tid;
    const int t_l = u >> 3;
    const int kg  = u & 7;
    hb[j] = h + ((size_t)(b * Tt + tb * 128 + t_l)) * Dd + kg * 8;
    const int kk  = kg >> 2;
    const int klo = kg & 3;
    baddr[j] = kk * 8192 + (t_l >> 6) * 4096 + ((t_l >> 4) & 3) * 1024
             + (klo * 16 + ((t_l & 15) ^ kg)) * 16;
  }

  // ---- fragment read offsets (verified R16) ----
  const int aoff = (ow >> 1) * 16384 + (ow & 1) * 4096 + lane * 16;  // +kk*8192+n*1024
  const int klo_r = lane >> 4;
  const int rs0 = (klo_r * 16 + ((lane & 15) ^ klo_r)) * 16;
  const int rs1 = (klo_r * 16 + ((lane & 15) ^ klo_r ^ 4)) * 16;
  const int boff = tw * 4096;                                        // +kk*8192+m*1024+rs

  f32x4 acc[4][4] = {};   // [m = t-sub][n = o-sub]
  f32x4 br[4];
  f16x8 pk[2];

  // ---- prologue: load B(0); gll16 A(0); cvt+write Bl[0]; load B(1) ----
#pragma unroll
  for (int j = 0; j < 2; ++j) {
    br[2 * j]     = *(const f32x4*)(hb[j]);
    br[2 * j + 1] = *(const f32x4*)(hb[j] + 4);
  }
#pragma unroll
  for (int q = 0; q < 4; ++q)
    gll16(Asrc[q], &Al[0][0] + q * 8192 + w * 1024);
#pragma unroll
  for (int j = 0; j < 2; ++j) {   // cvt waits B(0) (oldest 4) -> vmcnt(4), A(0) stays in flight
    f16x8 t;
#pragma unroll
    for (int m2 = 0; m2 < 4; ++m2) {
      t[m2]     = (_Float16)br[2 * j][m2];
      t[4 + m2] = (_Float16)br[2 * j + 1][m2];
    }
    pk[j] = t;
    *(f16x8*)(&Bl[0][0] + baddr[j]) = t;
  }
#pragma unroll
  for (int j = 0; j < 2; ++j) {   // B(1) -> br
    br[2 * j]     = *(const f32x4*)(hb[j] + 64);
    br[2 * j + 1] = *(const f32x4*)(hb[j] + 64 + 4);
  }
  asm volatile("s_waitcnt lgkmcnt(0)" ::: "memory");   // Bl[0] writes retired
  __builtin_amdgcn_sched_barrier(0);

#pragma unroll 1
  for (int ks = 0; ks < 16; ++ks) {
    const int cur = ks & 1;
    const int nxt = cur ^ 1;
    // top invariant: outstanding = A(ks) x4 [oldest] + B(ks+1) x4 [newest]
    asm volatile("s_waitcnt vmcnt(4)" ::: "memory");   // A(ks) landed (own segs)
    __builtin_amdgcn_sched_barrier(0);
    __builtin_amdgcn_s_barrier();                      // everyone's A(ks)+B(ks) ready
    __builtin_amdgcn_sched_barrier(0);
    // stage A(ks+1) -> Al[nxt] (readers finished before this barrier)
    {
      const size_t ko = (size_t)((ks + 1) & 15) << 14;
#pragma unroll
      for (int q = 0; q < 4; ++q)
        gll16(Asrc[q] + ko, &Al[nxt][0] + q * 8192 + w * 1024);
    }
    // cvt br (=B(ks+1)) -> pk; reg-dep wait = vmcnt(4) (leaves A(ks+1) in flight)
#pragma unroll
    for (int j = 0; j < 2; ++j) {
      f16x8 t;
#pragma unroll
      for (int m2 = 0; m2 < 4; ++m2) {
        t[m2]     = (_Float16)br[2 * j][m2];
        t[4 + m2] = (_Float16)br[2 * j + 1][m2];
      }
      pk[j] = t;
      *(f16x8*)(&Bl[nxt][0] + baddr[j]) = t;           // B(ks+1) -> Bl[nxt]
    }
    // issue br = B(ks+2) (wrapped tail; stays in flight across the next barrier)
    {
      const int kso = ((ks + 2) & 15) * 64;
#pragma unroll
      for (int j = 0; j < 2; ++j) {
        br[2 * j]     = *(const f32x4*)(hb[j] + kso);
        br[2 * j + 1] = *(const f32x4*)(hb[j] + kso + 4);
      }
    }
    __builtin_amdgcn_sched_barrier(0);
    // ---- kk=0 half: 8 ds_read + 16 MFMA ----
    {
      f16x8 af[4], bf[4];
#pragma unroll
      for (int n = 0; n < 4; ++n)
        af[n] = *(const f16x8*)(&Al[cur][0] + aoff + n * 1024);
#pragma unroll
      for (int m = 0; m < 4; ++m)
        bf[m] = *(const f16x8*)(&Bl[cur][0] + boff + m * 1024 + rs0);
      asm volatile("s_waitcnt lgkmcnt(0)" ::: "memory");
      __builtin_amdgcn_sched_barrier(0);
      __builtin_amdgcn_s_setprio(1);
#pragma unroll
      for (int m = 0; m < 4; ++m)
#pragma unroll
        for (int n = 0; n < 4; ++n)
          acc[m][n] = __builtin_amdgcn_mfma_f32_16x16x32_f16(af[n], bf[m],
                                                             acc[m][n], 0, 0, 0);
      __builtin_amdgcn_s_setprio(0);
    }
    // ---- kk=1 half: reads hide under kk0's MFMA drain ----
    {
      f16x8 af[4], bf[4];
#pragma unroll
      for (int n = 0; n < 4; ++n)
        af[n] = *(const f16x8*)(&Al[cur][0] + aoff + 8192 + n * 1024);
#pragma unroll
      for (int m = 0; m < 4; ++m)
        bf[m] = *(const f16x8*)(&Bl[cur][0] + boff + 8192 + m * 1024 + rs1);
      asm volatile("s_waitcnt lgkmcnt(0)" ::: "memory");
      __builtin_amdgcn_sched_barrier(0);
      __builtin_amdgcn_s_setprio(1);
#pragma unroll
      for (int m = 0; m < 4; ++m)
#pragma unroll
        for (int n = 0; n < 4; ++n)
          acc[m][n] = __builtin_amdgcn_mfma_f32_16x16x32_f16(af[n], bf[m],
                                                             acc[m][n], 0, 0, 0);
      __builtin_amdgcn_s_setprio(0);
    }
  }

  // ---- epilogue: tanh + v-weight + reduce over o (verified R16) ----
  const float* wbase = w2_ws + b * Dd + obb * 256;
  const float* vbase = v_a + obb * 256;
  float ep[4] = {0.f, 0.f, 0.f, 0.f};
#pragma unroll
  for (int n = 0; n < 4; ++n) {
    const int og = ow * 64 + n * 16 + ((lane >> 4) << 2);
    const f32x4 w4 = *(const f32x4*)(wbase + og);
    const f32x4 v4 = *(const f32x4*)(vbase + og);
#pragma unroll
    for (int m = 0; m < 4; ++m)
#pragma unroll
      for (int r = 0; r < 4; ++r) {
        const float x = __builtin_fmaf(acc[m][n][r], 2.f, w4[r]);
        ep[m] += v4[r] * (1.f - 2.f / (__expf(x) + 1.f));
      }
  }
#pragma unroll
  for (int m = 0; m < 4; ++m) {
    ep[m] += __shfl_xor(ep[m], 16, 64);
    ep[m] += __shfl_xor(ep[m], 32, 64);
  }
  __syncthreads();   // drains outstanding vmem/lds; orders exch reuse
  if (lane < 16) {
#pragma unroll
    for (int m = 0; m < 4; ++m)
      exch[ow * 128 + tw * 64 + m * 16 + lane] = ep[m];
  }
  __syncthreads();
  if (tid < 128) {
    const float sv = exch[tid] + exch[128 + tid] + exch[256 + tid] + exch[384 + tid];
    e_part[((size_t)(obb * Bb + b)) * Tt + tb * 128 + tid] = sv;
  }
}

// ---------------- kernel 4: reduce 4 o-partials + softmax over T per b ----------------
__global__ __launch_bounds__(256) void k_sm(const float* __restrict__ e_part,
                                            float* __restrict__ a_ws) {
  const int b = blockIdx.x;
  const int lane = threadIdx.x & 63;
  const int wv = threadIdx.x >> 6;
  __shared__ float red[8];
  float ev[8];
  float m = -1e30f;
#pragma unroll
  for (int j = 0; j < 8; ++j) {
    const int t = threadIdx.x + 256 * j;
    float sv = 0.f;
#pragma unroll
    for (int o = 0; o < 4; ++o) sv += e_part[((size_t)(o * Bb + b)) * Tt + t];
    ev[j] = sv;
    m = fmaxf(m, sv);
  }
#pragma unroll
  for (int sft = 1; sft < 64; sft <<= 1) m = fmaxf(m, __shfl_xor(m, sft, 64));
  if (lane == 0) red[wv] = m;
  __syncthreads();
  m = fmaxf(fmaxf(red[0], red[1]), fmaxf(red[2], red[3]));
  float sum = 0.f;
#pragma unroll
  for (int j = 0; j < 8; ++j) { ev[j] = __expf(ev[j] - m); sum += ev[j]; }
#pragma unroll
  for (int sft = 1; sft < 64; sft <<= 1) sum += __shfl_xor(sum, sft, 64);
  if (lane == 0) red[4 + wv] = sum;
  __syncthreads();
  const float inv = 1.f / (red[4] + red[5] + red[6] + red[7]);
#pragma unroll
  for (int j = 0; j < 8; ++j) a_ws[b * Tt + threadIdx.x + 256 * j] = ev[j] * inv;
}

// ---------------- kernel 5a: partial c over 64-t chunks (deterministic) ----------------
__global__ __launch_bounds__(256) void k_c1(const float* __restrict__ h,
                                            const float* __restrict__ a_ws,
                                            float* __restrict__ cpart) {
  const int b  = blockIdx.x >> 5;
  const int tc = blockIdx.x & 31;
  const int t0 = tc << 6;
  __shared__ float a_sh[64];
  if (threadIdx.x < 64) a_sh[threadIdx.x] = a_ws[b * Tt + t0 + threadIdx.x];
  __syncthreads();
  f32x4 acc = {0.f, 0.f, 0.f, 0.f};
  const float* hb = h + ((size_t)b * Tt + t0) * Dd + threadIdx.x * 4;
#pragma unroll 4
  for (int t = 0; t < 64; ++t) {
    const f32x4 hv = *(const f32x4*)(hb + (size_t)t * Dd);
    acc += a_sh[t] * hv;
  }
  *(f32x4*)(cpart + ((size_t)(tc * 32 + b) << 10) + threadIdx.x * 4) = acc;
}

// ---------------- kernel 5b: reduce partials, store f32 ----------------
__global__ __launch_bounds__(256) void k_c2(const float* __restrict__ cpart,
                                            float* __restrict__ out) {
  const int gid = blockIdx.x * 256 + threadIdx.x;   // 0..32767
  const int b = gid >> 10;
  const int d = gid & 1023;
  float sv = 0.f;
#pragma unroll
  for (int tc = 0; tc < 32; ++tc) sv += cpart[((size_t)(tc * 32 + b) << 10) + d];
  out[gid] = sv;
}

extern "C" void kernel_launch(void* const* d_in, const int* in_sizes, int n_in,
                              void* d_out, int out_size, void* d_ws, size_t ws_size,
                              hipStream_t stream) {
  (void)in_sizes; (void)n_in; (void)out_size; (void)ws_size;
  const float* s  = (const float*)d_in[0];
  const float* h  = (const float*)d_in[1];
  const float* W  = (const float*)d_in[2];
  const float* U  = (const float*)d_in[3];
  const float* v  = (const float*)d_in[4];
  uint8_t* ws = (uint8_t*)d_ws;
  float*   w2_ws  = (float*)ws;
  float*   a_ws   = (float*)(ws + WS_A);
  float*   e_part = (float*)(ws + WS_EP);   // aliases cpart (sequential lifetimes)
  float*   cpart  = (float*)(ws + WS_EP);
  uint8_t* U_ts   = ws + WS_UT;

  k_ws<<<128, 256, 0, stream>>>(s, W, w2_ws);
  k_ut<<<256, 256, 0, stream>>>(U, U_ts);
  k_e <<<2048, 512, 0, stream>>>(h, U_ts, w2_ws, v, e_part);
  k_sm<<<Bb, 256, 0, stream>>>(e_part, a_ws);
  k_c1<<<1024, 256, 0, stream>>>(h, a_ws, cpart);
  k_c2<<<128, 256, 0, stream>>>(cpart, (float*)d_out);
}

// Round 19
// 312.511 us; speedup vs baseline: 1.0126x; 1.0126x over previous
//
#include <hip/hip_runtime.h>
#include <hip/hip_bf16.h>
#include <stdint.h>

#define Bb 32
#define Tt 2048
#define Dd 1024   // D_IN = D_H = D_OUT

typedef float    f32x4 __attribute__((ext_vector_type(4)));
typedef _Float16 f16x8 __attribute__((ext_vector_type(8)));
typedef uint32_t u32;

// ---- ws layout (bytes) ----
// 0        w2_ws  [32][1024] f32  (2 * s.W_a)          128K
// 131072   a_ws   [32][2048] f32                       256K
// 393216   UNION: e_part [4 obb][32 b][2048 t] f32 (1M, k_e->k_sm)
//                 cpart  [32 tc][32 b][1024] f32 (4M, k_c1->k_c2)
// 4587520  U_ts   tiled fp16 U^T (see k_ut)            2M
#define WS_A     131072
#define WS_EP    393216
#define WS_UT    4587520

__device__ __forceinline__ void gll16(const void* g, const void* lds) {
  __builtin_amdgcn_global_load_lds(
      (const __attribute__((address_space(1))) u32*)(uintptr_t)g,
      (__attribute__((address_space(3))) u32*)(uint32_t)(uintptr_t)lds,
      16, 0, 0);
}

// ---------------- kernel 1: w2[b][o] = 2 * sum_i s[b][i] * W[i][o] ----------------
__global__ __launch_bounds__(256) void k_ws(const float* __restrict__ s,
                                            const float* __restrict__ W,
                                            float* __restrict__ w2_ws) {
  const int b = blockIdx.x >> 2;
  const int o = (blockIdx.x & 3) * 256 + threadIdx.x;
  __shared__ float s_sh[Dd];
#pragma unroll
  for (int j = 0; j < 4; ++j)
    s_sh[threadIdx.x + 256 * j] = s[b * Dd + threadIdx.x + 256 * j];
  __syncthreads();
  float acc = 0.f;
#pragma unroll 8
  for (int i = 0; i < Dd; ++i) acc += s_sh[i] * W[(size_t)i * Dd + o];
  w2_ws[b * Dd + o] = 2.f * acc;
}

// ------- kernel 2: build U_ts, tile-major linear-lane layout (unchanged) -------
// Tile (ob 0..7, ks 0..15) = 16KB at (ob*16+ks)*16384; element (o_l, k_l):
// byte = (k_l>>5)*8192 + (o_l>>6)*4096 + ((o_l>>4)&3)*1024
//        + (((k_l>>3)&3)*16 + (o_l&15))*16 + (k_l&7)*2
__global__ __launch_bounds__(256) void k_ut(const float* __restrict__ U,
                                            uint8_t* __restrict__ U_ts) {
  const int i0 = (blockIdx.x >> 4) * 64;   // k-tile
  const int o0 = (blockIdx.x & 15) * 64;   // o-tile
  __shared__ float tile[64][65];           // [o_loc][k_loc]
  const int tx = threadIdx.x & 63;
  const int ty = threadIdx.x >> 6;
#pragma unroll
  for (int jj = 0; jj < 16; ++jj)
    tile[tx][ty + 4 * jj] = U[(size_t)(i0 + ty + 4 * jj) * Dd + o0 + tx];
  __syncthreads();
#pragma unroll
  for (int it = 0; it < 2; ++it) {
    const int g  = it * 256 + threadIdx.x;  // 0..511
    const int ol = g & 63;
    const int kg = g >> 6;                  // 0..7
    const int o  = o0 + ol;
    const int k  = i0 + kg * 8;
    f16x8 r;
#pragma unroll
    for (int m = 0; m < 8; ++m) r[m] = (_Float16)tile[ol][kg * 8 + m];
    const int ob  = o >> 7, ks = k >> 6;
    const int o_l = o & 127, k_l = k & 63;
    const size_t byte = ((size_t)(ob * 16 + ks) << 14)
                      + (size_t)((k_l >> 5) * 8192 + (o_l >> 6) * 4096
                      + ((o_l >> 4) & 3) * 1024
                      + (((k_l >> 3) & 3) * 16 + (o_l & 15)) * 16);
    *(f16x8*)(U_ts + byte) = r;
  }
}

// ---------------- kernel 3: fused GEMM, counted-drain split-phase step ----------------
// R16 geometry exactly (512 thr, 8 waves tw/ow, 128t x 256o, acc[4][4], LDS 51KB,
// 2 blk/CU). Step restructured: all staging ISSUED up front in pinned order
// [A-kk0 x2, A-kk1 x2, pk ds_write x2, br(ks+1) x4] -> outstanding known exactly.
//   lgkm(0); vmcnt(6)  -> A-kk0 landed (A-kk1 + br stay in flight)
//   barrier; kk0 frags + 16 MFMA          (covers A-kk1's DMA)
//   vmcnt(4)           -> A-kk1 landed (br stays in flight)
//   barrier; kk1 frags + 16 MFMA; cvt br->pk (reg-dep drains br)
// Same 2 barriers/step as R16 but no full vmcnt(0) drain anywhere.
__global__ __launch_bounds__(512, 3) void k_e(const float* __restrict__ h,
                                              const uint8_t* __restrict__ U_ts,
                                              const float* __restrict__ w2_ws,
                                              const float* __restrict__ v_a,
                                              float* __restrict__ e_part) {
  const int blk = blockIdx.x;
  const int b   = blk >> 6;
  const int obb = (blk >> 4) & 3;   // 256-o block
  const int tb  = blk & 15;         // 128-t tile (fastest -> obb-sharers same XCD)
  const int tid  = threadIdx.x;
  const int lane = tid & 63;
  const int w    = tid >> 6;   // 0..7
  const int tw   = w >> 2;     // t-half
  const int ow   = w & 3;      // o-quarter

  __shared__ __align__(16) uint8_t Al[32768];
  __shared__ __align__(16) uint8_t Bl[16384];
  __shared__ float exch[512];

  // ---- A staging addressing: 4 gll16/thread; q -> tile (obb*2 + (q>>1)), kk = q&1 ----
  const uint8_t* Asrc[4];
#pragma unroll
  for (int q = 0; q < 4; ++q)
    Asrc[q] = U_ts + ((size_t)((obb * 2 + (q >> 1)) * 16) << 14)
            + (size_t)(((q & 1) * 512 + w * 64 + lane) * 16);

  // ---- B addressing: 2 units/thread: u = j*512+tid -> t_l = u>>3, kg = u&7 ----
  const float* hb[2];
  int baddr[2];
#pragma unroll
  for (int j = 0; j < 2; ++j) {
    const int u   = j * 512 + tid;
    const int t_l = u >> 3;
    const int kg  = u & 7;
    hb[j] = h + ((size_t)(b * Tt + tb * 128 + t_l)) * Dd + kg * 8;
    const int kk  = kg >> 2;
    const int klo = kg & 3;
    baddr[j] = kk * 8192 + (t_l >> 6) * 4096 + ((t_l >> 4) & 3) * 1024
             + (klo * 16 + ((t_l & 15) ^ kg)) * 16;
  }

  // ---- fragment read offsets (verified R16) ----
  const int aoff = (ow >> 1) * 16384 + (ow & 1) * 4096 + lane * 16;  // +kk*8192+n*1024
  const int klo_r = lane >> 4;
  const int rs0 = (klo_r * 16 + ((lane & 15) ^ klo_r)) * 16;
  const int rs1 = (klo_r * 16 + ((lane & 15) ^ klo_r ^ 4)) * 16;
  const int boff = tw * 4096;                                        // +kk*8192+m*1024+rs

  f32x4 acc[4][4] = {};   // [m = t-sub][n = o-sub]
  f32x4 br[4];
  f16x8 pk[2];

  // ---- prologue: load B(0) -> br -> pk (outstanding drains to 0 via reg-dep) ----
#pragma unroll
  for (int j = 0; j < 2; ++j) {
    br[2 * j]     = *(const f32x4*)(hb[j]);
    br[2 * j + 1] = *(const f32x4*)(hb[j] + 4);
  }
#pragma unroll
  for (int j = 0; j < 2; ++j) {
    f16x8 t;
#pragma unroll
    for (int m2 = 0; m2 < 4; ++m2) {
      t[m2]     = (_Float16)br[2 * j][m2];
      t[4 + m2] = (_Float16)br[2 * j + 1][m2];
    }
    pk[j] = t;
  }

#pragma unroll 1
  for (int ks = 0; ks < 16; ++ks) {
    // b1: prev step's frag reads done everywhere; all LDS regions rewritable
    __builtin_amdgcn_sched_barrier(0);
    __builtin_amdgcn_s_barrier();
    __builtin_amdgcn_sched_barrier(0);
    // stage group (order PINNED): A-kk0, A-kk1, pk ds_write, br(ks+1)
    {
      const size_t ko = (size_t)ks << 14;
      gll16(Asrc[0] + ko, Al + 0 * 8192 + w * 1024);   // tile0 kk0
      gll16(Asrc[2] + ko, Al + 2 * 8192 + w * 1024);   // tile1 kk0
      __builtin_amdgcn_sched_barrier(0);
      gll16(Asrc[1] + ko, Al + 1 * 8192 + w * 1024);   // tile0 kk1
      gll16(Asrc[3] + ko, Al + 3 * 8192 + w * 1024);   // tile1 kk1
      __builtin_amdgcn_sched_barrier(0);
#pragma unroll
      for (int j = 0; j < 2; ++j) *(f16x8*)(Bl + baddr[j]) = pk[j];
      __builtin_amdgcn_sched_barrier(0);
      const int kso = ((ks + 1) & 15) * 64;
#pragma unroll
      for (int j = 0; j < 2; ++j) {
        br[2 * j]     = *(const f32x4*)(hb[j] + kso);
        br[2 * j + 1] = *(const f32x4*)(hb[j] + kso + 4);
      }
      __builtin_amdgcn_sched_barrier(0);
    }
    // outstanding vmem: A0(2 oldest) + A1(2) + br(4 newest) = 8
    asm volatile("s_waitcnt lgkmcnt(0)" ::: "memory");   // pk writes retired
    asm volatile("s_waitcnt vmcnt(6)" ::: "memory");     // A-kk0 landed
    __builtin_amdgcn_sched_barrier(0);
    __builtin_amdgcn_s_barrier();                        // everyone's kk0 + B ready
    __builtin_amdgcn_sched_barrier(0);
    // ---- kk0: 8 ds_read + 16 MFMA (covers A-kk1 DMA) ----
    {
      f16x8 af[4], bf[4];
#pragma unroll
      for (int n = 0; n < 4; ++n)
        af[n] = *(const f16x8*)(Al + aoff + n * 1024);
#pragma unroll
      for (int m = 0; m < 4; ++m)
        bf[m] = *(const f16x8*)(Bl + boff + m * 1024 + rs0);
      asm volatile("s_waitcnt lgkmcnt(0)" ::: "memory");
      __builtin_amdgcn_sched_barrier(0);
      __builtin_amdgcn_s_setprio(1);
#pragma unroll
      for (int m = 0; m < 4; ++m)
#pragma unroll
        for (int n = 0; n < 4; ++n)
          acc[m][n] = __builtin_amdgcn_mfma_f32_16x16x32_f16(af[n], bf[m],
                                                             acc[m][n], 0, 0, 0);
      __builtin_amdgcn_s_setprio(0);
    }
    // outstanding: A1(2 oldest) + br(4 newest) = 6
    asm volatile("s_waitcnt vmcnt(4)" ::: "memory");     // A-kk1 landed
    __builtin_amdgcn_sched_barrier(0);
    __builtin_amdgcn_s_barrier();                        // everyone's kk1 ready
    __builtin_amdgcn_sched_barrier(0);
    // ---- kk1: 8 ds_read + 16 MFMA, then cvt br->pk (drains br via reg-dep) ----
    {
      f16x8 af[4], bf[4];
#pragma unroll
      for (int n = 0; n < 4; ++n)
        af[n] = *(const f16x8*)(Al + aoff + 8192 + n * 1024);
#pragma unroll
      for (int m = 0; m < 4; ++m)
        bf[m] = *(const f16x8*)(Bl + boff + 8192 + m * 1024 + rs1);
      asm volatile("s_waitcnt lgkmcnt(0)" ::: "memory");
      __builtin_amdgcn_sched_barrier(0);
      __builtin_amdgcn_s_setprio(1);
#pragma unroll
      for (int m = 0; m < 4; ++m)
#pragma unroll
        for (int n = 0; n < 4; ++n)
          acc[m][n] = __builtin_amdgcn_mfma_f32_16x16x32_f16(af[n], bf[m],
                                                             acc[m][n], 0, 0, 0);
      __builtin_amdgcn_s_setprio(0);
    }
#pragma unroll
    for (int j = 0; j < 2; ++j) {
      f16x8 t;
#pragma unroll
      for (int m2 = 0; m2 < 4; ++m2) {
        t[m2]     = (_Float16)br[2 * j][m2];
        t[4 + m2] = (_Float16)br[2 * j + 1][m2];
      }
      pk[j] = t;
    }
  }

  // ---- epilogue: tanh + v-weight + reduce over o (verified R16) ----
  const float* wbase = w2_ws + b * Dd + obb * 256;
  const float* vbase = v_a + obb * 256;
  float ep[4] = {0.f, 0.f, 0.f, 0.f};
#pragma unroll
  for (int n = 0; n < 4; ++n) {
    const int og = ow * 64 + n * 16 + ((lane >> 4) << 2);
    const f32x4 w4 = *(const f32x4*)(wbase + og);
    const f32x4 v4 = *(const f32x4*)(vbase + og);
#pragma unroll
    for (int m = 0; m < 4; ++m)
#pragma unroll
      for (int r = 0; r < 4; ++r) {
        const float x = __builtin_fmaf(acc[m][n][r], 2.f, w4[r]);
        ep[m] += v4[r] * (1.f - 2.f / (__expf(x) + 1.f));
      }
  }
#pragma unroll
  for (int m = 0; m < 4; ++m) {
    ep[m] += __shfl_xor(ep[m], 16, 64);
    ep[m] += __shfl_xor(ep[m], 32, 64);
  }
  __syncthreads();   // full drain + orders exch use
  if (lane < 16) {
#pragma unroll
    for (int m = 0; m < 4; ++m)
      exch[ow * 128 + tw * 64 + m * 16 + lane] = ep[m];
  }
  __syncthreads();
  if (tid < 128) {
    const float sv = exch[tid] + exch[128 + tid] + exch[256 + tid] + exch[384 + tid];
    e_part[((size_t)(obb * Bb + b)) * Tt + tb * 128 + tid] = sv;
  }
}

// ---------------- kernel 4: reduce 4 o-partials + softmax over T per b ----------------
__global__ __launch_bounds__(256) void k_sm(const float* __restrict__ e_part,
                                            float* __restrict__ a_ws) {
  const int b = blockIdx.x;
  const int lane = threadIdx.x & 63;
  const int wv = threadIdx.x >> 6;
  __shared__ float red[8];
  float ev[8];
  float m = -1e30f;
#pragma unroll
  for (int j = 0; j < 8; ++j) {
    const int t = threadIdx.x + 256 * j;
    float sv = 0.f;
#pragma unroll
    for (int o = 0; o < 4; ++o) sv += e_part[((size_t)(o * Bb + b)) * Tt + t];
    ev[j] = sv;
    m = fmaxf(m, sv);
  }
#pragma unroll
  for (int sft = 1; sft < 64; sft <<= 1) m = fmaxf(m, __shfl_xor(m, sft, 64));
  if (lane == 0) red[wv] = m;
  __syncthreads();
  m = fmaxf(fmaxf(red[0], red[1]), fmaxf(red[2], red[3]));
  float sum = 0.f;
#pragma unroll
  for (int j = 0; j < 8; ++j) { ev[j] = __expf(ev[j] - m); sum += ev[j]; }
#pragma unroll
  for (int sft = 1; sft < 64; sft <<= 1) sum += __shfl_xor(sum, sft, 64);
  if (lane == 0) red[4 + wv] = sum;
  __syncthreads();
  const float inv = 1.f / (red[4] + red[5] + red[6] + red[7]);
#pragma unroll
  for (int j = 0; j < 8; ++j) a_ws[b * Tt + threadIdx.x + 256 * j] = ev[j] * inv;
}

// ---------------- kernel 5a: partial c over 64-t chunks (deterministic) ----------------
__global__ __launch_bounds__(256) void k_c1(const float* __restrict__ h,
                                            const float* __restrict__ a_ws,
                                            float* __restrict__ cpart) {
  const int b  = blockIdx.x >> 5;
  const int tc = blockIdx.x & 31;
  const int t0 = tc << 6;
  __shared__ float a_sh[64];
  if (threadIdx.x < 64) a_sh[threadIdx.x] = a_ws[b * Tt + t0 + threadIdx.x];
  __syncthreads();
  f32x4 acc = {0.f, 0.f, 0.f, 0.f};
  const float* hb = h + ((size_t)b * Tt + t0) * Dd + threadIdx.x * 4;
#pragma unroll 4
  for (int t = 0; t < 64; ++t) {
    const f32x4 hv = *(const f32x4*)(hb + (size_t)t * Dd);
    acc += a_sh[t] * hv;
  }
  *(f32x4*)(cpart + ((size_t)(tc * 32 + b) << 10) + threadIdx.x * 4) = acc;
}

// ---------------- kernel 5b: reduce partials, store f32 ----------------
__global__ __launch_bounds__(256) void k_c2(const float* __restrict__ cpart,
                                            float* __restrict__ out) {
  const int gid = blockIdx.x * 256 + threadIdx.x;   // 0..32767
  const int b = gid >> 10;
  const int d = gid & 1023;
  float sv = 0.f;
#pragma unroll
  for (int tc = 0; tc < 32; ++tc) sv += cpart[((size_t)(tc * 32 + b) << 10) + d];
  out[gid] = sv;
}

extern "C" void kernel_launch(void* const* d_in, const int* in_sizes, int n_in,
                              void* d_out, int out_size, void* d_ws, size_t ws_size,
                              hipStream_t stream) {
  (void)in_sizes; (void)n_in; (void)out_size; (void)ws_size;
  const float* s  = (const float*)d_in[0];
  const float* h  = (const float*)d_in[1];
  const float* W  = (const float*)d_in[2];
  const float* U  = (const float*)d_in[3];
  const float* v  = (const float*)d_in[4];
  uint8_t* ws = (uint8_t*)d_ws;
  float*   w2_ws  = (float*)ws;
  float*   a_ws   = (float*)(ws + WS_A);
  float*   e_part = (float*)(ws + WS_EP);   // aliases cpart (sequential lifetimes)
  float*   cpart  = (float*)(ws + WS_EP);
  uint8_t* U_ts   = ws + WS_UT;

  k_ws<<<128, 256, 0, stream>>>(s, W, w2_ws);
  k_ut<<<256, 256, 0, stream>>>(U, U_ts);
  k_e <<<2048, 512, 0, stream>>>(h, U_ts, w2_ws, v, e_part);
  k_sm<<<Bb, 256, 0, stream>>>(e_part, a_ws);
  k_c1<<<1024, 256, 0, stream>>>(h, a_ws, cpart);
  k_c2<<<128, 256, 0, stream>>>(cpart, (float*)d_out);
}